// Round 12
// baseline (64.082 us; speedup 1.0000x reference)
//
#include <hip/hip_runtime.h>
#include <hip/hip_bf16.h>

// LengthRegulator: x [B=32,T=512,D=512] f32, duration [B,T] int32, max_len=4096.
// out0: [B,ML,D] f32, out1: mel_len [B] f32.
//
// R11 lesson: fused scan worse than split (60.5 vs 58.1) -> bubble is small.
// R12: fill-shaped main kernel. 256-thread blocks (fill kernel's shape):
//   - expand: 1 phoneme/wave, 4 waves/block, 4096 tiny blocks.
//   - zerofill: per-batch GRID-STRIDE over [mel, ML) like fillBufferAligned
//     (reads 1 csum int, balanced for any mel).
//   - expand/zero blocks interleaved per batch to mix R/W streams evenly.

typedef float f32x4 __attribute__((ext_vector_type(4)));

constexpr int B   = 32;
constexpr int T   = 512;
constexpr int D   = 512;
constexpr int D4  = D / 4;        // 128 x 16B per row
constexpr int ML  = 4096;
constexpr int kScanThreads = 512;
constexpr int kMainThreads = 256;                  // fill kernel's shape
constexpr int kNumE  = T / 4;                      // 128 expand blocks / batch
constexpr int kNumZ  = 64;                         // zerofill blocks / batch
constexpr int kBPB   = kNumE + kNumZ;              // 192 blocks / batch
constexpr int kZStride = kNumZ * kMainThreads;     // grid-stride span (threads)

__global__ __launch_bounds__(kScanThreads) void lr_scan(
    const int* __restrict__ duration,   // [B, T]
    int*       __restrict__ csum,       // [B, T] (d_ws)
    float*     __restrict__ mel_out)    // [B]
{
    const int b = blockIdx.x;
    const int t = threadIdx.x;
    const int lane = t & 63;
    const int wave = t >> 6;

    __shared__ int wsum[kScanThreads / 64];

    int v = duration[b * T + t];
    #pragma unroll
    for (int off = 1; off < 64; off <<= 1) {
        int n = __shfl_up(v, off, 64);
        if (lane >= off) v += n;
    }
    if (lane == 63) wsum[wave] = v;
    __syncthreads();
    int prev = 0;
    #pragma unroll
    for (int w = 0; w < kScanThreads / 64; ++w)
        if (w < wave) prev += wsum[w];
    v += prev;
    csum[b * T + t] = v;
    if (t == T - 1)
        mel_out[b] = (float)v;
}

__global__ __launch_bounds__(kMainThreads) void lr_main(
    const int*   __restrict__ csum,     // [B, T]
    const f32x4* __restrict__ x,        // [B, T, D4]
    f32x4*       __restrict__ out)      // [B, ML, D4]
{
    const int bid  = blockIdx.x;
    const int b    = bid / kBPB;
    const int r    = bid % kBPB;
    const int t    = threadIdx.x;
    const int lane = t & 63;
    const int wave = t >> 6;            // 4 waves

    if (r < kNumE) {
        // ---- expand: this wave owns phoneme p ----
        const int p = r * 4 + wave;
        const int e = csum[b * T + p];
        const int s = (p == 0) ? 0 : csum[b * T + p - 1];
        if (e > s) {
            const size_t xb = ((size_t)(b * T + p)) * D4;
            const f32x4 v0 = x[xb + lane];        // first 1KB of row
            const f32x4 v1 = x[xb + 64 + lane];   // second 1KB
            size_t o = ((size_t)(b * ML + s)) * D4;
            for (int j = s; j < e; ++j, o += D4) {
                out[o + lane]      = v0;          // full-line 1KB stores
                out[o + 64 + lane] = v1;
            }
        }
    } else {
        // ---- zerofill: grid-stride over [mel, ML) like fillBuffer ----
        const int c   = r - kNumE;                 // 0..kNumZ-1
        const int mel = csum[b * T + T - 1];
        const int n4  = (ML - mel) * D4;           // f32x4 count of tail
        const size_t base = ((size_t)(b * ML + mel)) * D4;
        const f32x4 zero = {0.f, 0.f, 0.f, 0.f};
        for (int m = c * kMainThreads + t; m < n4; m += kZStride)
            out[base + m] = zero;
    }
}

extern "C" void kernel_launch(void* const* d_in, const int* in_sizes, int n_in,
                              void* d_out, int out_size, void* d_ws, size_t ws_size,
                              hipStream_t stream) {
    const float* x   = (const float*)d_in[0];
    const int*   dur = (const int*)d_in[1];

    float* out     = (float*)d_out;                 // [B*ML*D] then [B]
    float* mel_out = out + (size_t)B * ML * D;
    int*   csum    = (int*)d_ws;                    // B*T ints = 64KB

    lr_scan<<<B, kScanThreads, 0, stream>>>(dur, csum, mel_out);
    lr_main<<<B * kBPB, kMainThreads, 0, stream>>>(csum, (const f32x4*)x, (f32x4*)out);
}

// Round 13
// 58.436 us; speedup vs baseline: 1.0966x; 1.0966x over previous
//
#include <hip/hip_runtime.h>
#include <hip/hip_bf16.h>

// LengthRegulator: x [B=32,T=512,D=512] f32, duration [B,T] int32, max_len=4096.
// out0: [B,ML,D] f32, out1: mel_len [B] f32.
//
// FINAL (R10 structure, best measured 58.08us):
//   kernel 1 (32 blocks): scan duration -> csum in d_ws + mel_out.
//   kernel 2 (4096 uniform fine blocks, NO scan prologue):
//     - expand: 1 phoneme/wave (8 waves/block), row 2KB single-touch,
//       plain full-line 1KB stores.
//     - zerofill: 64-frame (128KB) chunks, pure stores.
// Probed and rejected: NT-gather (58.2), fused barrier-free scan (60.5),
// fill-shaped 256t blocks (64.1), coarse blocks (63-66), NT-vs-plain (tie).
// 302 MB mandatory traffic / 58us = 5.2 TB/s ~= 83% of the 6.29 TB/s mixed
// copy ceiling -> read/write turnaround bound. Practical roofline.

typedef float f32x4 __attribute__((ext_vector_type(4)));

constexpr int B   = 32;
constexpr int T   = 512;
constexpr int D   = 512;
constexpr int D4  = D / 4;        // 128 x 16B per row
constexpr int ML  = 4096;
constexpr int NTHREADS = 512;
constexpr int kZChunk = 64;                    // frames per zerofill block (128KB)
constexpr int kNumZ   = ML / kZChunk;          // 64 zerofill blocks / batch
constexpr int kNumE   = T / 8;                 // 64 expand blocks / batch
constexpr int kBPB    = kNumE + kNumZ;         // 128 blocks per batch

__global__ __launch_bounds__(NTHREADS) void lr_scan(
    const int* __restrict__ duration,   // [B, T]
    int*       __restrict__ csum,       // [B, T] (d_ws)
    float*     __restrict__ mel_out)    // [B]
{
    const int b = blockIdx.x;
    const int t = threadIdx.x;
    const int lane = t & 63;
    const int wave = t >> 6;

    __shared__ int wsum[NTHREADS / 64];

    int v = duration[b * T + t];
    #pragma unroll
    for (int off = 1; off < 64; off <<= 1) {
        int n = __shfl_up(v, off, 64);
        if (lane >= off) v += n;
    }
    if (lane == 63) wsum[wave] = v;
    __syncthreads();
    int prev = 0;
    #pragma unroll
    for (int w = 0; w < NTHREADS / 64; ++w)
        if (w < wave) prev += wsum[w];
    v += prev;
    csum[b * T + t] = v;
    if (t == T - 1)
        mel_out[b] = (float)v;
}

__global__ __launch_bounds__(NTHREADS) void lr_main(
    const int*   __restrict__ csum,     // [B, T]
    const f32x4* __restrict__ x,        // [B, T, D4]
    f32x4*       __restrict__ out)      // [B, ML, D4]
{
    const int bid  = blockIdx.x;
    const int b    = bid / kBPB;
    const int r    = bid % kBPB;
    const int t    = threadIdx.x;
    const int lane = t & 63;
    const int wave = t >> 6;

    if (r < kNumE) {
        // ---- expand: this wave owns phoneme p ----
        const int p   = r * 8 + wave;
        const int e   = csum[b * T + p];
        const int s   = (p == 0) ? 0 : csum[b * T + p - 1];
        if (e > s) {
            const size_t xb = ((size_t)(b * T + p)) * D4;
            const f32x4 v0 = x[xb + lane];        // first 1KB of row
            const f32x4 v1 = x[xb + 64 + lane];   // second 1KB of row
            size_t o = ((size_t)(b * ML + s)) * D4;
            for (int j = s; j < e; ++j, o += D4) {
                out[o + lane]      = v0;          // full-line 1KB stores
                out[o + 64 + lane] = v1;
            }
        }
    } else {
        // ---- zerofill: frames [max(j0, mel), j0 + kZChunk) ----
        const int c   = r - kNumE;
        const int mel = csum[b * T + T - 1];
        const int j0  = c * kZChunk;
        const int lo  = (j0 > mel) ? j0 : mel;
        const int hi  = j0 + kZChunk;
        if (lo < hi) {
            const f32x4 zero = {0.f, 0.f, 0.f, 0.f};
            const size_t base = ((size_t)(b * ML + lo)) * D4;
            const int total = (hi - lo) * D4;
            for (int m = t; m < total; m += NTHREADS)
                out[base + m] = zero;
        }
    }
}

extern "C" void kernel_launch(void* const* d_in, const int* in_sizes, int n_in,
                              void* d_out, int out_size, void* d_ws, size_t ws_size,
                              hipStream_t stream) {
    const float* x   = (const float*)d_in[0];
    const int*   dur = (const int*)d_in[1];

    float* out     = (float*)d_out;                 // [B*ML*D] then [B]
    float* mel_out = out + (size_t)B * ML * D;
    int*   csum    = (int*)d_ws;                    // B*T ints = 64KB

    lr_scan<<<B, NTHREADS, 0, stream>>>(dur, csum, mel_out);
    lr_main<<<B * kBPB, NTHREADS, 0, stream>>>(csum, (const f32x4*)x, (f32x4*)out);
}